// Round 3
// baseline (1398.376 us; speedup 1.0000x reference)
//
#include <hip/hip_runtime.h>
#include <math.h>

#define NN 4096
#define EE 65536
#define H 128
#define NF 4
#define MNODE 8
#define MEDGE 4
#define NT 2

// ---------------- CSR build ----------------
__global__ void k_count(const int* __restrict__ dst, int* __restrict__ cnt) {
  int e = blockIdx.x * 256 + threadIdx.x;
  if (e < EE) atomicAdd(&cnt[dst[e]], 1);
}

__global__ void k_scan(const int* __restrict__ cnt, int* __restrict__ rp) {
  __shared__ int sh[1024];
  int t = threadIdx.x;
  int v0 = cnt[4*t], v1 = cnt[4*t+1], v2 = cnt[4*t+2], v3 = cnt[4*t+3];
  int p1 = v0, p2 = v0 + v1, p3 = p2 + v2, tot = p3 + v3;
  sh[t] = tot; __syncthreads();
  for (int off = 1; off < 1024; off <<= 1) {
    int add = (t >= off) ? sh[t-off] : 0;
    __syncthreads();
    sh[t] += add;
    __syncthreads();
  }
  int base = sh[t] - tot;
  rp[4*t] = base; rp[4*t+1] = base + p1; rp[4*t+2] = base + p2; rp[4*t+3] = base + p3;
  if (t == 1023) rp[NN] = sh[t];
}

__global__ void k_fill(const int* __restrict__ ei, int* __restrict__ cursor, int* __restrict__ cols) {
  int e = blockIdx.x * 256 + threadIdx.x;
  if (e < EE) {
    int d = ei[EE + e], s = ei[e];
    int pos = atomicAdd(&cursor[d], 1);
    cols[pos] = s;
  }
}

__global__ void k_dinv0(const int* __restrict__ cnt, float* __restrict__ d2, float* __restrict__ d1) {
  int i = blockIdx.x * 256 + threadIdx.x;
  if (i < NN) {
    float c = (float)cnt[i];
    d2[i] = 1.f / sqrtf(c + 2.f);
    d1[i] = 1.f / sqrtf(c + 1.f);
  }
}

__global__ void k_pwnorm(const float* __restrict__ pw, float* __restrict__ pwn) {
  int l = blockIdx.x, t = threadIdx.x; // 64 threads
  float a = pw[l*H + t], b = pw[l*H + 64 + t];
  float s = a*a + b*b;
  for (int off = 32; off > 0; off >>= 1) s += __shfl_down(s, off);
  if (t == 0) pwn[l] = sqrtf(s);
}

__global__ void k_segS(const int* __restrict__ dst, const float* __restrict__ me, float* __restrict__ S) {
  int e = blockIdx.x * 256 + threadIdx.x;
  if (e < EE) {
    int d = dst[e];
#pragma unroll
    for (int m = 0; m < MEDGE; m++) atomicAdd(&S[d*MEDGE + m], me[e*MEDGE + m]);
  }
}

// ---------------- fused edge-MLP projections: P = na@Wm[0:140], Q = na@Wm[140:280]
// na = cat([F, mn, h]) built on the fly; A-indices block-uniform -> scalar loads.
__global__ void k_mmPQ(const float* __restrict__ F, const float* __restrict__ mn,
                       const float* __restrict__ h, const float* __restrict__ Wm,
                       float* __restrict__ P, float* __restrict__ Q) {
  constexpr int R = 8;
  int row0 = blockIdx.x * R;
  int t = threadIdx.x; // 128
  float accP[R] = {}, accQ[R] = {};
#pragma unroll
  for (int kk = 0; kk < NF; kk++) {
    float b1 = Wm[kk*H + t], b2 = Wm[(140 + kk)*H + t];
#pragma unroll
    for (int r = 0; r < R; r++) {
      float a = F[(row0 + r)*NF + kk];
      accP[r] += a*b1; accQ[r] += a*b2;
    }
  }
#pragma unroll
  for (int kk = 0; kk < MNODE; kk++) {
    float b1 = Wm[(NF + kk)*H + t], b2 = Wm[(140 + NF + kk)*H + t];
#pragma unroll
    for (int r = 0; r < R; r++) {
      float a = mn[(row0 + r)*MNODE + kk];
      accP[r] += a*b1; accQ[r] += a*b2;
    }
  }
#pragma unroll 2
  for (int kk = 0; kk < H; kk++) {
    float b1 = Wm[(12 + kk)*H + t], b2 = Wm[(152 + kk)*H + t];
#pragma unroll
    for (int r = 0; r < R; r++) {
      float a = h[(size_t)(row0 + r)*H + kk];
      accP[r] += a*b1; accQ[r] += a*b2;
    }
  }
#pragma unroll
  for (int r = 0; r < R; r++) {
    P[(size_t)(row0 + r)*H + t] = accP[r];
    Q[(size_t)(row0 + r)*H + t] = accQ[r];
  }
}

// h1 = relu(cnt_i*(P_i+bm) + (A@Q)_i + S_i@WmB)
__global__ void k_spmm_h1(const float* __restrict__ Q, const int* __restrict__ rp,
                          const int* __restrict__ cols, const float* __restrict__ P,
                          const float* __restrict__ bm, const float* __restrict__ S,
                          const float* __restrict__ WmB, const int* __restrict__ cnt,
                          float* __restrict__ h1) {
  int i = blockIdx.x, t = threadIdx.x;
  float acc = 0.f;
  int beg = rp[i], end = rp[i+1];
  for (int e = beg; e < end; e++) acc += Q[(size_t)cols[e]*H + t];
  float v = (float)cnt[i] * (P[(size_t)i*H + t] + bm[t]) + acc;
#pragma unroll
  for (int m = 0; m < MEDGE; m++) v += S[i*MEDGE + m] * WmB[m*H + t];
  h1[(size_t)i*H + t] = fmaxf(v, 0.f);
}

// row-blocked 128xK GEMM: C[row] = scale(row) * (A[rows[row]] @ B), K=128
// perm/sv optional (pooled-x fusion), dinv optional.
__global__ void k_mm_multi(const float* __restrict__ A, const float* __restrict__ B,
                           float* __restrict__ C, int nrows, const float* __restrict__ dinv,
                           const int* __restrict__ perm, const float* __restrict__ sv) {
  constexpr int R = 8;
  int row0 = blockIdx.x * R;
  int t = threadIdx.x; // 128
  float acc[R] = {};
  int rows[R];
#pragma unroll
  for (int r = 0; r < R; r++) {
    int row = row0 + r;
    rows[r] = (row < nrows) ? (perm ? perm[row] : row) : 0;
  }
#pragma unroll 4
  for (int kk = 0; kk < H; kk++) {
    float b = B[kk*H + t];
#pragma unroll
    for (int r = 0; r < R; r++) acc[r] += A[(size_t)rows[r]*H + kk] * b;
  }
#pragma unroll
  for (int r = 0; r < R; r++) {
    int row = row0 + r;
    if (row < nrows) {
      float scale = (dinv ? dinv[row] : 1.f) * (sv ? sv[row] : 1.f);
      C[(size_t)row*H + t] = acc[r] * scale;
    }
  }
}

// SpMM over CSR rows; if dinv!=null apply GCN epilogue
__global__ void k_spmm_fused(const float* __restrict__ ts, const int* __restrict__ rp,
                             const int* __restrict__ cols, const float* __restrict__ dinv,
                             float fill, const float* __restrict__ bias, int relu,
                             float* __restrict__ out) {
  int i = blockIdx.x, t = threadIdx.x;
  float acc = 0.f;
  int beg = rp[i], end = rp[i+1];
  for (int e = beg; e < end; e++) acc += ts[(size_t)cols[e]*H + t];
  float v;
  if (dinv) {
    v = dinv[i] * (acc + fill * ts[(size_t)i*H + t]) + bias[t];
    if (relu) v = fmaxf(v, 0.f);
  } else v = acc;
  out[(size_t)i*H + t] = v;
}

// ---------------- top-k pooling (rank-based, exact jax.lax.top_k semantics) ---------
// score + sortable key + rank zeroing. 4 rows/block (1 per wave).
__global__ void k_score4(const float* __restrict__ x, const float* __restrict__ pw,
                         const float* __restrict__ pwn, int lvl, int n,
                         float* __restrict__ score, unsigned long long* __restrict__ keys,
                         int* __restrict__ rank) {
  int w = threadIdx.x >> 6, lane = threadIdx.x & 63;
  int row = blockIdx.x * 4 + w;
  if (row >= n) return;
  float s = x[(size_t)row*H + lane]*pw[lane] + x[(size_t)row*H + 64 + lane]*pw[64 + lane];
  for (int off = 32; off > 0; off >>= 1) s += __shfl_down(s, off);
  if (lane == 0) {
    float sc = tanhf(s / pwn[lvl]);
    score[row] = sc;
    unsigned u = __float_as_uint(sc + 0.0f);          // canonicalize -0.0
    u ^= ((unsigned)((int)u >> 31)) | 0x80000000u;    // ascending-sortable
    keys[row] = ((unsigned long long)u << 12) | (unsigned)(4095 - row);
    rank[row] = 0;
  }
}

// partial rank counts: block (bi,bj) counts keys in j-chunk [bj*512, ...) greater than key_i
__global__ void k_rankp(const unsigned long long* __restrict__ keys, int n,
                        int* __restrict__ rank) {
  __shared__ unsigned long long kj[512];
  int t = threadIdx.x;
  int j0 = blockIdx.y * 512;
  int jn = n - j0; if (jn > 512) jn = 512;
  for (int j = t; j < 512; j += 256) kj[j] = (j < jn) ? keys[j0 + j] : 0ULL; // 0 never wins
  __syncthreads();
  int i = blockIdx.x * 256 + t;
  if (i >= n) return;
  unsigned long long ki = keys[i];
  int r = 0;
  const ulonglong2* k2 = (const ulonglong2*)kj;
#pragma unroll 8
  for (int j = 0; j < 256; j++) {
    ulonglong2 v = k2[j];
    r += (v.x > ki) ? 1 : 0;
    r += (v.y > ki) ? 1 : 0;
  }
  if (r > 0) atomicAdd(&rank[i], r);
}

__global__ void k_rscatter(const int* __restrict__ rank, const float* __restrict__ score,
                           int n, int k, int* __restrict__ perm, float* __restrict__ sv) {
  int i = blockIdx.x * 256 + threadIdx.x;
  if (i < n) {
    int r = rank[i];
    if (r < k) { perm[r] = i; sv[r] = score[i]; }
  }
}

// A_820[r,c] = (A1@A1)[perm_r, perm_c], diag zeroed; A1 = offdiag(A0)+I via CSR.
// Fused: dv[r] = rsqrt(rowsum + 2).
__global__ void k_a820(const int* __restrict__ rp, const int* __restrict__ cols,
                       const int* __restrict__ perm, float* __restrict__ A820,
                       float* __restrict__ dv) {
  __shared__ float acc[NN];
  __shared__ float red[256];
  int r = blockIdx.x, t = threadIdx.x;
  for (int i = t; i < NN; i += 256) acc[i] = 0.f;
  __syncthreads();
  int pi = perm[r];
  int beg = rp[pi], end = rp[pi+1];
  for (int e = beg + t; e < end; e += 256) { int c = cols[e]; if (c != pi) atomicAdd(&acc[c], 1.f); }
  if (t == 0) atomicAdd(&acc[pi], 1.f);
  for (int e0 = beg; e0 < end; e0++) {
    int c = cols[e0];
    if (c == pi) continue;
    int b2 = rp[c], e2 = rp[c+1];
    for (int e = b2 + t; e < e2; e += 256) { int c2 = cols[e]; if (c2 != c) atomicAdd(&acc[c2], 1.f); }
    if (t == 0) atomicAdd(&acc[c], 1.f);
  }
  __syncthreads();
  float psum = 0.f;
  for (int cc = t; cc < 820; cc += 256) {
    float v = (cc == r) ? 0.f : acc[perm[cc]];
    A820[(size_t)r*820 + cc] = v;
    psum += v;
  }
  red[t] = psum; __syncthreads();
  for (int off = 128; off > 0; off >>= 1) { if (t < off) red[t] += red[t+off]; __syncthreads(); }
  if (t == 0) dv[r] = 1.f / sqrtf(red[0] + 2.f);
}

// dense level augment+pool: out[r,c] = (A^2)[pr,pc] + 2*A[pr,pc] (r!=c), 0 diag.
// Fused: dv[r] = rsqrt(rowsum + 2).
__global__ void k_augpool(const float* __restrict__ A, int n, const int* __restrict__ perm,
                          int knext, float* __restrict__ out, float* __restrict__ dv) {
  __shared__ float rowb[832];
  __shared__ float red[256];
  int r = blockIdx.x, t = threadIdx.x;
  int pr = perm[r];
  for (int i = t; i < n; i += 256) rowb[i] = A[(size_t)pr*n + i];
  __syncthreads();
  float psum = 0.f;
  for (int c = t; c < knext; c += 256) {
    int pc = perm[c];
    float dot = 0.f;
    for (int kk = 0; kk < n; kk++) {
      float rv = rowb[kk];
      if (rv != 0.f) dot += rv * A[(size_t)kk*n + pc];
    }
    float v = (c == r) ? 0.f : (dot + 2.f * rowb[pc]);
    out[(size_t)r*knext + c] = v;
    psum += v;
  }
  red[t] = psum; __syncthreads();
  for (int off = 128; off > 0; off >>= 1) { if (t < off) red[t] += red[t+off]; __syncthreads(); }
  if (t == 0) dv[r] = 1.f / sqrtf(red[0] + 2.f);
}

// dense GCN apply: out[i,:] = dinv_i*(sum_k A[i,k]*ts[k,:] + fill*ts[i,:]) + b (+relu)
__global__ void k_dense_gcn(const float* __restrict__ A, int n, const float* __restrict__ ts,
                            const float* __restrict__ dinv, float fill, const float* __restrict__ bias,
                            int relu, float* __restrict__ out) {
  __shared__ float arow[128];
  int i = blockIdx.x, t = threadIdx.x;
  float acc = 0.f;
  for (int k0 = 0; k0 < n; k0 += H) {
    int m = (n - k0 < H) ? (n - k0) : H;
    if (t < m) arow[t] = A[(size_t)i*n + k0 + t];
    __syncthreads();
    for (int kk = 0; kk < m; kk++) {
      float a = arow[kk];
      if (a != 0.f) acc += a * ts[(size_t)(k0 + kk)*H + t];
    }
    __syncthreads();
  }
  float v = dinv[i] * (acc + fill * ts[(size_t)i*H + t]) + bias[t];
  if (relu) v = fmaxf(v, 0.f);
  out[(size_t)i*H + t] = v;
}

// up-path: tmp[i] = res[i] + (rank[i]<k ? xcur[rank[i]] : 0)
__global__ void k_upmix(const float* __restrict__ res, const int* __restrict__ rank, int k,
                        const float* __restrict__ xc, float* __restrict__ tmp) {
  int i = blockIdx.x, t = threadIdx.x;
  int r = rank[i];
  float add = (r < k) ? xc[(size_t)r*H + t] : 0.f;
  tmp[(size_t)i*H + t] = res[(size_t)i*H + t] + add;
}

// ts2[row,0:4] = dinv1_row * (cat([h1, relu(hbuf)]) @ Wout)[row,:]
__global__ void k_outproj(const float* __restrict__ h1, const float* __restrict__ hbuf,
                          const float* __restrict__ Wout, const float* __restrict__ dinv1,
                          float* __restrict__ ts2) {
  int row = blockIdx.x, t = threadIdx.x; // 64 threads
  float p0 = 0.f, p1 = 0.f, p2 = 0.f, p3 = 0.f;
#pragma unroll
  for (int half = 0; half < 2; half++) {
    float a = h1[(size_t)row*H + half*64 + t];
    const float* w = Wout + (half*64 + t)*4;
    p0 += a*w[0]; p1 += a*w[1]; p2 += a*w[2]; p3 += a*w[3];
    float b = fmaxf(hbuf[(size_t)row*H + half*64 + t], 0.f);
    const float* w2 = Wout + (128 + half*64 + t)*4;
    p0 += b*w2[0]; p1 += b*w2[1]; p2 += b*w2[2]; p3 += b*w2[3];
  }
  for (int off = 32; off > 0; off >>= 1) {
    p0 += __shfl_down(p0, off); p1 += __shfl_down(p1, off);
    p2 += __shfl_down(p2, off); p3 += __shfl_down(p3, off);
  }
  if (t == 0) {
    float d = dinv1[row];
    ts2[row*4+0] = d*p0; ts2[row*4+1] = d*p1; ts2[row*4+2] = d*p2; ts2[row*4+3] = d*p3;
  }
}

__global__ void k_gcn_out(const float* __restrict__ ts2, const int* __restrict__ rp,
                          const int* __restrict__ cols, const float* __restrict__ dinv1,
                          const float* __restrict__ bout, float* __restrict__ Fcur,
                          float* __restrict__ dout, int tstep) {
  int i = blockIdx.x, t = threadIdx.x; // 64 threads
  int f = t & 3;
  float acc = 0.f;
  int beg = rp[i], end = rp[i+1];
  for (int e = beg + (t >> 2); e < end; e += 16) acc += ts2[cols[e]*4 + f];
  for (int off = 32; off >= 4; off >>= 1) acc += __shfl_down(acc, off);
  if (t < 4) {
    float v = dinv1[i] * (acc + ts2[i*4 + f]) + bout[f];
    Fcur[i*4 + f] = v;
    dout[i*(NT*NF) + tstep*NF + f] = v;
  }
}

extern "C" void kernel_launch(void* const* d_in, const int* in_sizes, int n_in,
                              void* d_out, int out_size, void* d_ws, size_t ws_size,
                              hipStream_t stream) {
  const float* F0        = (const float*)d_in[0];
  const float* mesh_node = (const float*)d_in[1];
  const float* mesh_edge = (const float*)d_in[2];
  const float* Wm        = (const float*)d_in[3];
  const float* bm        = (const float*)d_in[4];
  const float* Wd0       = (const float*)d_in[5];
  const float* bd0       = (const float*)d_in[6];
  const float* Wd        = (const float*)d_in[7];
  const float* bd        = (const float*)d_in[8];
  const float* pool_w    = (const float*)d_in[9];
  const float* Wu        = (const float*)d_in[10];
  const float* bu        = (const float*)d_in[11];
  const float* Wout      = (const float*)d_in[12];
  const float* bout      = (const float*)d_in[13];
  const int*   ei        = (const int*)d_in[14];
  float* out = (float*)d_out;

  char* p = (char*)d_ws;
  auto carve = [&](size_t bytes) -> char* {
    char* r = p;
    p += (bytes + 255) & ~(size_t)255;
    return r;
  };
  int*   cnt    = (int*)carve((size_t)NN*4);
  int*   rp     = (int*)carve((size_t)(NN+1)*4);
  int*   cursor = (int*)carve((size_t)NN*4);
  int*   cols   = (int*)carve((size_t)EE*4);
  int*   permb  = (int*)carve((size_t)5*832*4);
  float* svb    = (float*)carve((size_t)5*832*4);
  int*   rankb  = (int*)carve((size_t)5*NN*4);
  unsigned long long* keys = (unsigned long long*)carve((size_t)NN*8);
  float* dinv2  = (float*)carve((size_t)NN*4);
  float* dinv1  = (float*)carve((size_t)NN*4);
  float* pwn    = (float*)carve(8*4);
  float* S      = (float*)carve((size_t)NN*MEDGE*4);
  float* P      = (float*)carve((size_t)NN*H*4);
  float* Q      = (float*)carve((size_t)NN*H*4);
  float* h1     = (float*)carve((size_t)NN*H*4);
  float* hbuf   = (float*)carve((size_t)NN*H*4);
  float* tsb    = (float*)carve((size_t)NN*H*4);
  float* tmp    = (float*)carve((size_t)NN*H*4);
  float* x0     = (float*)carve((size_t)NN*H*4);
  float* x1     = (float*)carve((size_t)820*H*4);
  float* x2     = (float*)carve((size_t)164*H*4);
  float* x3     = (float*)carve((size_t)33*H*4);
  float* x4     = (float*)carve((size_t)7*H*4);
  float* xcur   = (float*)carve((size_t)820*H*4);
  float* score  = (float*)carve((size_t)NN*4);
  float* A820   = (float*)carve((size_t)820*820*4);
  float* A164   = (float*)carve((size_t)164*164*4);
  float* A33    = (float*)carve((size_t)33*33*4);
  float* A7     = (float*)carve((size_t)7*7*4);
  float* A2b    = (float*)carve((size_t)2*2*4);
  float* dv820  = (float*)carve(820*4);
  float* dv164  = (float*)carve(164*4);
  float* dv33   = (float*)carve(33*4);
  float* dv7    = (float*)carve(7*4);
  float* dv2    = (float*)carve(2*4);
  float* ts2    = (float*)carve((size_t)NN*NF*4);
  float* Fcur   = (float*)carve((size_t)NN*NF*4);

  const int KLh[5]  = {820, 164, 33, 7, 2};
  const int szs[5]  = {4096, 820, 164, 33, 7};
  float* Adense[5] = {A820, A164, A33, A7, A2b};
  float* dvl[5]    = {dv820, dv164, dv33, dv7, dv2};
  float* xsv[5]    = {x0, x1, x2, x3, x4};
  int* perml[5]; float* svl[5]; int* rankl[5];
  for (int l = 0; l < 5; l++) {
    perml[l] = permb + l*832; svl[l] = svb + l*832; rankl[l] = rankb + l*NN;
  }

  // ---- setup (once per launch) ----
  hipMemsetAsync(cnt, 0, (size_t)NN*4, stream);
  hipMemsetAsync(S, 0, (size_t)NN*MEDGE*4, stream);
  hipMemsetAsync(hbuf, 0, (size_t)NN*H*4, stream);
  k_count<<<EE/256, 256, 0, stream>>>(ei + EE, cnt);
  k_scan<<<1, 1024, 0, stream>>>(cnt, rp);
  hipMemcpyAsync(cursor, rp, (size_t)NN*4, hipMemcpyDeviceToDevice, stream);
  k_fill<<<EE/256, 256, 0, stream>>>(ei, cursor, cols);
  k_dinv0<<<NN/256, 256, 0, stream>>>(cnt, dinv2, dinv1);
  k_pwnorm<<<5, 64, 0, stream>>>(pool_w, pwn);
  k_segS<<<EE/256, 256, 0, stream>>>(ei + EE, mesh_edge, S);
  hipMemcpyAsync(Fcur, F0, (size_t)NN*NF*4, hipMemcpyDeviceToDevice, stream);

  for (int step = 0; step < NT; step++) {
    // edge MLP (factored) -> h1
    k_mmPQ<<<NN/8, 128, 0, stream>>>(Fcur, mesh_node, hbuf, Wm, P, Q);
    k_spmm_h1<<<NN, 128, 0, stream>>>(Q, rp, cols, P, bm, S, Wm + 280*H, cnt, h1);

    // down GCN0 at 4096 (fill=2), relu
    k_mm_multi<<<NN/8, 128, 0, stream>>>(h1, Wd0, tsb, NN, dinv2, nullptr, nullptr);
    k_spmm_fused<<<NN, 128, 0, stream>>>(tsb, rp, cols, dinv2, 2.f, bd0, 1, x0);

    // down path
    for (int i = 0; i < 5; i++) {
      int n_prev = szs[i], k = KLh[i];
      k_score4<<<(n_prev + 3)/4, 256, 0, stream>>>(xsv[i], pool_w + i*H, pwn, i, n_prev,
                                                   score, keys, rankl[i]);
      dim3 rg((n_prev + 255)/256, (n_prev + 511)/512);
      k_rankp<<<rg, 256, 0, stream>>>(keys, n_prev, rankl[i]);
      k_rscatter<<<(n_prev + 255)/256, 256, 0, stream>>>(rankl[i], score, n_prev, k,
                                                         perml[i], svl[i]);
      if (i == 0) k_a820<<<820, 256, 0, stream>>>(rp, cols, perml[0], Adense[0], dvl[0]);
      else        k_augpool<<<k, 256, 0, stream>>>(Adense[i-1], n_prev, perml[i], k,
                                                   Adense[i], dvl[i]);
      k_mm_multi<<<(k + 7)/8, 128, 0, stream>>>(xsv[i], Wd + i*H*H, tsb, k, dvl[i],
                                                perml[i], svl[i]);
      float* outx = (i < 4) ? xsv[i+1] : xcur;
      k_dense_gcn<<<k, 128, 0, stream>>>(Adense[i], k, tsb, dvl[i], 2.f, bd + i*H, 1, outx);
    }

    // up path
    for (int i = 0; i < 5; i++) {
      int j = 4 - i;
      int n = szs[j], kk = KLh[j];
      k_upmix<<<n, 128, 0, stream>>>(xsv[j], rankl[j], kk, xcur, tmp);
      if (j > 0) {
        k_mm_multi<<<(n + 7)/8, 128, 0, stream>>>(tmp, Wu + i*H*H, tsb, n, dvl[j-1],
                                                  nullptr, nullptr);
        k_dense_gcn<<<n, 128, 0, stream>>>(Adense[j-1], n, tsb, dvl[j-1], 2.f, bu + i*H,
                                           (i < 4) ? 1 : 0, xcur);
      } else {
        k_mm_multi<<<(n + 7)/8, 128, 0, stream>>>(tmp, Wu + i*H*H, tsb, n, dinv2,
                                                  nullptr, nullptr);
        k_spmm_fused<<<n, 128, 0, stream>>>(tsb, rp, cols, dinv2, 2.f, bu + i*H, 0, hbuf);
      }
    }

    // output GCN (fill=1); relu fused into outproj
    k_outproj<<<NN, 64, 0, stream>>>(h1, hbuf, Wout, dinv1, ts2);
    k_gcn_out<<<NN, 64, 0, stream>>>(ts2, rp, cols, dinv1, bout, Fcur, out, step);
  }
}